// Round 8
// baseline (342.383 us; speedup 1.0000x reference)
//
#include <hip/hip_runtime.h>
#include <hip/hip_bf16.h>

// MoE top-2, d=1024, E=8, N=8192 tokens. Grouped-GEMM design:
//   prep(transpose||gate fused) -> fillplan -> GEMM1(relu) -> GEMM2(+atomic combine)
// R4-R8: all in-block schedule knobs null (11-12% MfmaUtil). R9 crash = launch_bounds
//   forced reg cap. R10 banked 325us. R11: 128x64 tile, occupancy 23->45% but time only
//   117->109us -> TLP saturated too; residual = per-tile fixed costs (prologue/epilogue/
//   dispatch tail; K=1024 gives only 32 iters to amortize vs m97's 128) + structural
//   2-phase stall.
// R12: (a) persistent k_gemm: 1088 blocks = 8 XCD x 136 slots, exactly 2 tiles/block
//   (same XCD-local tile ownership as R11), R11 inner loop verbatim; tail removed,
//   epilogue stores drain under next tile's prologue DMAs.
//   (b) transpose+gate fused into one launch (independent work, LDS union);
//   gate emits per-block gcnt (plain stores), fillplan reduces -> no counts init dep.

#define NTOK   8192
#define DM     1024
#define NE     8
#define BM     128
#define NSLOT  (NTOK * 2)
#define PADCAP (NSLOT + NE * BM)      // 17408
#define MAXTILES (PADCAP / BM)        // 136
#define NGATE  512                    // gate blocks in k_prep

typedef __attribute__((ext_vector_type(8))) short  bf16x8;
typedef __attribute__((ext_vector_type(4))) float  f32x4;
typedef __attribute__((ext_vector_type(8))) unsigned short u16x8;

__device__ __forceinline__ unsigned short f2bf(float f) {
    union { float f; unsigned u; } v; v.f = f;
    unsigned r = v.u + 0x7fffu + ((v.u >> 16) & 1u);
    return (unsigned short)(r >> 16);
}

// async global->LDS DMA, 16B per lane; dest = wave-uniform base + lane*16
__device__ __forceinline__ void load_lds16(const ushort* g, ushort* l) {
    __builtin_amdgcn_global_load_lds(
        (const __attribute__((address_space(1))) unsigned int*)g,
        (__attribute__((address_space(3))) unsigned int*)l,
        16, 0, 0);
}

// ---------- fused prep: blocks [0,512) = gate, [512,4608) = weight transpose ----------
// Independent work co-scheduled in one dispatch (BW-bound transpose || VALU-bound gate).
// LDS union: transpose t[64][65] (16.3KB) vs gate wgT[8][1024] (32KB) -> 32KB smem.
__global__ __launch_bounds__(256) void k_prep(const float* __restrict__ W1,
                                              const float* __restrict__ W2,
                                              ushort* __restrict__ w1t,
                                              ushort* __restrict__ w2t,
                                              const float* __restrict__ x,
                                              const float* __restrict__ Wg,
                                              const float* __restrict__ bg,
                                              ushort* __restrict__ xb,
                                              int* __restrict__ tok_e,
                                              float* __restrict__ tok_w,
                                              int* __restrict__ gcnt,
                                              float* __restrict__ out,
                                              int* __restrict__ slot_token,
                                              int* __restrict__ cursor) {
    __shared__ float smem[NE * DM];   // 32 KB union
    __shared__ int cnt[NE];
    int gb = blockIdx.x, tid = threadIdx.x;

    if (gb >= NGATE) {
        // ---- transpose part: Wt[e][n][k] = W[e][k][n], cast to bf16 ----
        int tb = gb - NGATE;
        int ez = tb >> 8;
        const float* W = (ez < 8 ? W1 : W2) + (size_t)(ez & 7) * DM * DM;
        ushort* Wt = (ez < 8 ? w1t : w2t) + (size_t)(ez & 7) * DM * DM;
        float (*t)[65] = reinterpret_cast<float(*)[65]>(smem);
        int kt = ((tb >> 4) & 15) * 64, nt = (tb & 15) * 64;
        int r16 = tid >> 4, c4 = (tid & 15) * 4;
#pragma unroll
        for (int p = 0; p < 4; p++) {
            int k = p * 16 + r16;
            float4 v = *(const float4*)&W[(size_t)(kt + k) * DM + nt + c4];
            t[k][c4] = v.x; t[k][c4 + 1] = v.y; t[k][c4 + 2] = v.z; t[k][c4 + 3] = v.w;
        }
        __syncthreads();
        int n = tid >> 2, kb = (tid & 3) * 16;
#pragma unroll
        for (int h = 0; h < 2; h++) {
            int k0 = kb + h * 8;
            u16x8 o;
#pragma unroll
            for (int i = 0; i < 8; i++) o[i] = f2bf(t[k0 + i][n]);
            *(u16x8*)&Wt[(size_t)(nt + n) * DM + kt + k0] = o;
        }
        return;
    }

    // ---- gate part: scores = x@Wg + bg (fp32), top-2; casts x->bf16; zeroing ----
    float (*wgT)[DM] = reinterpret_cast<float(*)[DM]>(smem);
    if (gb == 0 && tid < NE) cursor[tid] = 0;
    if (tid < NE) cnt[tid] = 0;
    {
        float4 z4 = {0.f, 0.f, 0.f, 0.f};
        float4* orow = (float4*)(out + (size_t)gb * 16 * DM);
#pragma unroll
        for (int i = 0; i < 16; i++) orow[i * 256 + tid] = z4;
        int s0 = gb * (PADCAP / NGATE);
        for (int i = tid; i < PADCAP / NGATE; i += 256) slot_token[s0 + i] = -1;
    }
    for (int i = tid; i < DM * NE; i += 256) {
        int d = i >> 3, e = i & 7;
        wgT[e][d] = Wg[i];
    }
    __syncthreads();
    int wave = tid >> 6, lane = tid & 63;
    int n0 = (gb * 4 + wave) * 4;
    const float4* xr[4];
#pragma unroll
    for (int t = 0; t < 4; t++) xr[t] = (const float4*)(x + (size_t)(n0 + t) * DM);

    float acc[4][NE];
#pragma unroll
    for (int t = 0; t < 4; t++)
#pragma unroll
        for (int e = 0; e < NE; e++) acc[t][e] = 0.f;

#pragma unroll
    for (int j = 0; j < 4; j++) {
        float4 xv[4];
#pragma unroll
        for (int t = 0; t < 4; t++) xv[t] = xr[t][j * 64 + lane];
#pragma unroll
        for (int t = 0; t < 4; t++) {
            ushort4 o;
            o.x = f2bf(xv[t].x); o.y = f2bf(xv[t].y);
            o.z = f2bf(xv[t].z); o.w = f2bf(xv[t].w);
            ((ushort4*)xb)[(size_t)(n0 + t) * (DM / 4) + j * 64 + lane] = o;
        }
#pragma unroll
        for (int e = 0; e < NE; e++) {
            float4 wv = ((const float4*)&wgT[e][0])[j * 64 + lane];
#pragma unroll
            for (int t = 0; t < 4; t++) {
                acc[t][e] += xv[t].x * wv.x + xv[t].y * wv.y
                           + xv[t].z * wv.z + xv[t].w * wv.w;
            }
        }
    }
#pragma unroll
    for (int t = 0; t < 4; t++)
#pragma unroll
        for (int e = 0; e < NE; e++) {
#pragma unroll
            for (int off = 32; off >= 1; off >>= 1)
                acc[t][e] += __shfl_xor(acc[t][e], off);
        }
    if (lane < 4) {
        int t = lane, n = n0 + t;
        float sc[NE];
#pragma unroll
        for (int e = 0; e < NE; e++) sc[e] = acc[t][e] + bg[e];
        int e0 = 0; float v0 = sc[0];
#pragma unroll
        for (int e = 1; e < NE; e++) if (sc[e] > v0) { v0 = sc[e]; e0 = e; }
        int e1 = -1; float v1 = -3.0e38f;
#pragma unroll
        for (int e = 0; e < NE; e++) if (e != e0 && sc[e] > v1) { v1 = sc[e]; e1 = e; }
        tok_e[2 * n] = e0;     tok_w[2 * n] = v0;
        tok_e[2 * n + 1] = e1; tok_w[2 * n + 1] = v1;
        atomicAdd(&cnt[e0], 1);
        atomicAdd(&cnt[e1], 1);
    }
    __syncthreads();
    if (tid < NE) gcnt[gb * NE + tid] = cnt[tid];   // plain store, no init needed
}

// ---------- fill + plan: reduce gcnt -> totals, hierarchical cursor, scatter ----------
__global__ __launch_bounds__(256) void k_fillplan(const int* __restrict__ tok_e,
                                                  const float* __restrict__ tok_w,
                                                  const int* __restrict__ gcnt,
                                                  int* __restrict__ cursor,
                                                  int* __restrict__ slot_token,
                                                  float* __restrict__ slot_w,
                                                  int* __restrict__ tile_e,
                                                  int* __restrict__ tile_b,
                                                  int* __restrict__ ntiles) {
    __shared__ int lcnt[NE], lbase[NE], wsum[4][NE];
    int tid = threadIdx.x;
    if (tid < NE) lcnt[tid] = 0;
    // total counts = sum over gcnt[512][8]
    int tot[NE];
#pragma unroll
    for (int e = 0; e < NE; e++) tot[e] = 0;
    for (int r = tid; r < NGATE; r += 256)
#pragma unroll
        for (int e = 0; e < NE; e++) tot[e] += gcnt[r * NE + e];
#pragma unroll
    for (int e = 0; e < NE; e++)
#pragma unroll
        for (int off = 32; off >= 1; off >>= 1) tot[e] += __shfl_xor(tot[e], off);
    int wave = tid >> 6, lane = tid & 63;
    if (lane == 0)
#pragma unroll
        for (int e = 0; e < NE; e++) wsum[wave][e] = tot[e];
    __syncthreads();   // publishes wsum + lcnt zero
#pragma unroll
    for (int e = 0; e < NE; e++)
        tot[e] = wsum[0][e] + wsum[1][e] + wsum[2][e] + wsum[3][e];

    int n = blockIdx.x * 256 + tid;
    int e0 = tok_e[2 * n],     e1 = tok_e[2 * n + 1];
    float w0 = tok_w[2 * n],   w1 = tok_w[2 * n + 1];
    int p0 = atomicAdd(&lcnt[e0], 1);
    int p1 = atomicAdd(&lcnt[e1], 1);
    __syncthreads();
    if (tid < NE) lbase[tid] = atomicAdd(&cursor[tid], lcnt[tid]);
    if (blockIdx.x == 0 && tid == 32) {   // different wave than the cursor atomics
        int t = 0, o2 = 0;
        for (int e = 0; e < NE; e++) {
            int nt = (tot[e] + BM - 1) / BM;
            for (int i = 0; i < nt; i++) { tile_e[t] = e; tile_b[t] = o2 + i * BM; t++; }
            o2 += nt * BM;
        }
        *ntiles = t;
    }
    __syncthreads();
    int base[NE]; int off = 0;
#pragma unroll
    for (int e = 0; e < NE; e++) {
        base[e] = off;
        off += ((tot[e] + BM - 1) / BM) * BM;
    }
    int s0 = base[e0] + lbase[e0] + p0;
    slot_token[s0] = n; slot_w[s0] = w0;
    int s1 = base[e1] + lbase[e1] + p1;
    slot_token[s1] = n; slot_w[s1] = w1;
}

// ---------- grouped GEMM: persistent, 128x64 tile, BK=32, double-buffered (R11 core) ----------
// 1088 blocks = 8 XCD x 136 slots; block (xcd,slot) owns local tile-cols {slot, slot+136}
// of its XCD's 272 (same XCD-local ownership as R11's swizzle) -> exactly 2 tiles/block,
// zero dispatch tail; tile j+1's prologue DMAs overlap tile j's epilogue store drain.
// Inner loop = R11 verbatim: 3 DMA/wave/iter, vmcnt(3), raw barriers + R6 fences,
// conflict-free 4-seg xor staging, setprio around MFMA. LDS 24KB, ~44 VGPR + 32 acc.
template <int PHASE>
__global__ __launch_bounds__(256) void k_gemm(const ushort* __restrict__ A,
                                              const ushort* __restrict__ Wt,
                                              const float* __restrict__ bias,
                                              const int* __restrict__ slot_token,
                                              const float* __restrict__ slot_w,
                                              const int* __restrict__ tile_e,
                                              const int* __restrict__ tile_b,
                                              const int* __restrict__ ntiles,
                                              ushort* __restrict__ Hout,
                                              float* __restrict__ out) {
    __shared__ ushort As[2][4096];   // [buf][row*32 + segpos*8], 128 rows
    __shared__ ushort Bs[2][2048];   // [buf][row*32 + segpos*8],  64 rows

    int tid = threadIdx.x;
    int wave = tid >> 6, lane = tid & 63, quad = lane >> 4, lm = lane & 15;
    int wm = wave >> 1, wn = wave & 1;
    int sr = lane >> 2;                            // row-in-chunk 0..15
    int gseg = (lane & 3) ^ ((lane >> 4) & 3);     // global 16B-seg (xor swizzle)
    int asel = ((quad ^ (lm >> 2)) & 3) * 8;
    int abase = (wm * 64 + lm) * 32 + asel;
    int bbase = (wn * 32 + lm) * 32 + asel;

    int xcd = blockIdx.x & 7, slot = blockIdx.x >> 3;   // slot 0..135
    int ntv = *ntiles;

#define ISSUE(buf, koff)                                              \
    do {                                                              \
        load_lds16(aptr[0] + (koff), &As[(buf)][(wave * 2 + 0) * 512]); \
        load_lds16(aptr[1] + (koff), &As[(buf)][(wave * 2 + 1) * 512]); \
        load_lds16(bptr + (koff), &Bs[(buf)][wave * 512]);            \
    } while (0)

#define COMPUTE(buf)                                                          \
    do {                                                                      \
        const ushort* Ab = As[(buf)];                                         \
        const ushort* Bb = Bs[(buf)];                                         \
        bf16x8 av[4], bv[2];                                                  \
        _Pragma("unroll")                                                     \
        for (int f = 0; f < 4; f++) av[f] = *(const bf16x8*)&Ab[abase + f * 512]; \
        _Pragma("unroll")                                                     \
        for (int f = 0; f < 2; f++) bv[f] = *(const bf16x8*)&Bb[bbase + f * 512]; \
        __builtin_amdgcn_s_setprio(1);                                        \
        _Pragma("unroll")                                                     \
        for (int fm = 0; fm < 4; fm++)                                        \
            _Pragma("unroll")                                                 \
            for (int fn = 0; fn < 2; fn++)                                    \
                acc[fm][fn] = __builtin_amdgcn_mfma_f32_16x16x32_bf16(        \
                    av[fm], bv[fn], acc[fm][fn], 0, 0, 0);                    \
        __builtin_amdgcn_s_setprio(0);                                        \
    } while (0)

#pragma unroll 1
    for (int j = 0; j < 2; ++j) {
        int wid = xcd * 272 + slot + 136 * j;
        int t = wid >> 4;
        if (t >= ntv) continue;                  // uniform per block -> barrier-safe
        int ncol0 = (wid & 15) << 6;
        int e = tile_e[t];
        int sbase = tile_b[t];
        const ushort* Wte = Wt + (size_t)e * DM * DM;

        const ushort* aptr[2];
        const ushort* bptr;
#pragma unroll
        for (int ci = 0; ci < 2; ci++) {
            int row = (wave * 2 + ci) * 16 + sr;
            int ar;
            if (PHASE == 1) {
                ar = slot_token[sbase + row];
                if (ar < 0) ar = 0;          // pad rows: load row 0, discard in epilogue
            } else {
                ar = sbase + row;
            }
            aptr[ci] = A + (size_t)ar * DM + gseg * 8;
        }
        {
            int brow = wave * 16 + sr;
            bptr = Wte + (size_t)(ncol0 + brow) * DM + gseg * 8;
        }

        f32x4 acc[4][2];
#pragma unroll
        for (int i = 0; i < 4; i++)
#pragma unroll
            for (int jj = 0; jj < 2; jj++) acc[i][jj] = (f32x4){0.f, 0.f, 0.f, 0.f};

        ISSUE(0, 0);
#pragma unroll 2
        for (int it = 0; it < 32; ++it) {
            if (it < 31) {
                ISSUE((it + 1) & 1, (it + 1) * 32);
                __builtin_amdgcn_s_waitcnt(0x0F73);   // vmcnt(3): current buf's 3 done
            } else {
                __builtin_amdgcn_s_waitcnt(0x0F70);   // vmcnt(0): last buf done
            }
            __builtin_amdgcn_s_barrier();
            __builtin_amdgcn_sched_barrier(0);        // ds_reads may not hoist above
            COMPUTE(it & 1);
            __builtin_amdgcn_sched_barrier(0);        // nothing sinks below
            __builtin_amdgcn_s_waitcnt(0xC07F);       // lgkmcnt(0): ds_reads retired
            __builtin_amdgcn_s_barrier();             // readers done before buf re-staged
        }

        // epilogue — C/D layout: col = lane&15, row = quad*4 + r  [m89-verified]
#pragma unroll
        for (int fm = 0; fm < 4; fm++) {
            int rowg = wm * 64 + fm * 16 + quad * 4;
            if (PHASE == 1) {
#pragma unroll
                for (int fn = 0; fn < 2; fn++) {
                    int col = ncol0 + wn * 32 + fn * 16 + lm;
                    float bv2 = bias[e * DM + col];
#pragma unroll
                    for (int r = 0; r < 4; r++) {
                        float v = acc[fm][fn][r] + bv2;
                        v = fmaxf(v, 0.f);
                        Hout[(size_t)(sbase + rowg + r) * DM + col] = f2bf(v);
                    }
                }
            } else {
                int tk[4]; float wv[4];
#pragma unroll
                for (int r = 0; r < 4; r++) {
                    tk[r] = slot_token[sbase + rowg + r];
                    wv[r] = slot_w[sbase + rowg + r];
                }
#pragma unroll
                for (int fn = 0; fn < 2; fn++) {
                    int col = ncol0 + wn * 32 + fn * 16 + lm;
                    float bv2 = bias[e * DM + col];
#pragma unroll
                    for (int r = 0; r < 4; r++) {
                        if (tk[r] >= 0) {
                            float v = wv[r] * (acc[fm][fn][r] + bv2);
                            atomicAdd(&out[(size_t)tk[r] * DM + col], v);
                        }
                    }
                }
            }
        }
    }
#undef ISSUE
#undef COMPUTE
}

extern "C" void kernel_launch(void* const* d_in, const int* in_sizes, int n_in,
                              void* d_out, int out_size, void* d_ws, size_t ws_size,
                              hipStream_t stream) {
    const float* x  = (const float*)d_in[0];
    const float* Wg = (const float*)d_in[1];
    const float* bg = (const float*)d_in[2];
    const float* W1 = (const float*)d_in[3];
    const float* b1 = (const float*)d_in[4];
    const float* W2 = (const float*)d_in[5];
    const float* b2 = (const float*)d_in[6];
    float* out = (float*)d_out;

    char* ws = (char*)d_ws;
    // workspace layout (bytes) — total ~86.3 MB
    ushort* xb         = (ushort*)(ws + 0);            // 16 MB
    ushort* w1t        = (ushort*)(ws + 16777216);     // 16 MB
    ushort* w2t        = (ushort*)(ws + 33554432);     // 16 MB
    ushort* H          = (ushort*)(ws + 50331648);     // 34 MB (PADCAP*DM*2)
    int*    tok_e      = (int*)  (ws + 85983232);
    float*  tok_w      = (float*)(ws + 86048768);
    int*    slot_token = (int*)  (ws + 86114304);
    float*  slot_w     = (float*)(ws + 86183936);
    int*    cursor     = (int*)  (ws + 86253568);
    int*    tile_e     = cursor + 16;
    int*    tile_b     = tile_e + MAXTILES;
    int*    ntiles     = tile_b + MAXTILES;
    int*    gcnt       = (int*)  (ws + 86257664);      // 512*8 ints = 16 KB

    k_prep<<<NGATE + 4096, 256, 0, stream>>>(W1, W2, w1t, w2t,
                                             x, Wg, bg, xb, tok_e, tok_w,
                                             gcnt, out, slot_token, cursor);
    k_fillplan<<<NTOK / 256, 256, 0, stream>>>(tok_e, tok_w, gcnt, cursor,
                                               slot_token, slot_w,
                                               tile_e, tile_b, ntiles);

    dim3 gg(8 * MAXTILES);   // 1088 persistent blocks, 2 tiles each
    k_gemm<1><<<gg, 256, 0, stream>>>(xb, w1t, b1, slot_token, slot_w,
                                      tile_e, tile_b, ntiles, H, nullptr);
    k_gemm<2><<<gg, 256, 0, stream>>>(H, w2t, b2, slot_token, slot_w,
                                      tile_e, tile_b, ntiles, nullptr, out);
}

// Round 9
// 332.346 us; speedup vs baseline: 1.0302x; 1.0302x over previous
//
#include <hip/hip_runtime.h>
#include <hip/hip_bf16.h>

// MoE top-2, d=1024, E=8, N=8192 tokens. Grouped-GEMM design:
//   gate -> transpose(W1) -> fillplan -> [GEMM1(relu) + embedded W2-transpose] -> GEMM2
// R4-R12 gemm family model: throughput ~ waves/SIMD x MFMA/iter against a ~2-4k cyc
//   per-block-iter wall no in-block knob moves; at 2176 natural tiles, concurrency
//   >~900 blocks hits grid-granularity tails -> gemm pair pinned ~215us in this family.
// R12 post-mortem: persistence neutral; prep fusion REGRESSED ~12us (32KB LDS union
//   halved transpose occupancy 9->5 blocks/CU).
// R13: (a) un-fuse prep (R10's separate gate/transpose kernels, full occupancy);
//   (b) transpose only W1 serially; W2-transpose blocks EMBEDDED in the GEMM1 dispatch
//   (blockIdx >= 1088 -> transpose branch; 16.6KB view fits gemm's 24KB LDS union ->
//   gemm occupancy unchanged; transpose backfills GEMM1's idle tail slots);
//   (c) k_gemm core = R12 verbatim (best measured).

#define NTOK   8192
#define DM     1024
#define NE     8
#define BM     128
#define NSLOT  (NTOK * 2)
#define PADCAP (NSLOT + NE * BM)      // 17408
#define MAXTILES (PADCAP / BM)        // 136
#define NGATE  512

typedef __attribute__((ext_vector_type(8))) short  bf16x8;
typedef __attribute__((ext_vector_type(4))) float  f32x4;
typedef __attribute__((ext_vector_type(8))) unsigned short u16x8;

__device__ __forceinline__ unsigned short f2bf(float f) {
    union { float f; unsigned u; } v; v.f = f;
    unsigned r = v.u + 0x7fffu + ((v.u >> 16) & 1u);
    return (unsigned short)(r >> 16);
}

// async global->LDS DMA, 16B per lane; dest = wave-uniform base + lane*16
__device__ __forceinline__ void load_lds16(const ushort* g, ushort* l) {
    __builtin_amdgcn_global_load_lds(
        (const __attribute__((address_space(1))) unsigned int*)g,
        (__attribute__((address_space(3))) unsigned int*)l,
        16, 0, 0);
}

// ---------- transpose + cast W1 only: w1t[e][n][k] = W1[e][k][n] ----------
__global__ __launch_bounds__(256) void k_transpose1(const float* __restrict__ W1,
                                                    ushort* __restrict__ w1t) {
    __shared__ float t[64][65];
    int e = blockIdx.z;
    const float* W = W1 + (size_t)e * DM * DM;
    ushort* Wt = w1t + (size_t)e * DM * DM;
    int kt = blockIdx.y * 64, nt = blockIdx.x * 64;
    int tid = threadIdx.x;
    int r16 = tid >> 4, c4 = (tid & 15) * 4;
#pragma unroll
    for (int p = 0; p < 4; p++) {
        int k = p * 16 + r16;
        float4 v = *(const float4*)&W[(size_t)(kt + k) * DM + nt + c4];
        t[k][c4] = v.x; t[k][c4 + 1] = v.y; t[k][c4 + 2] = v.z; t[k][c4 + 3] = v.w;
    }
    __syncthreads();
    int n = tid >> 2, kb = (tid & 3) * 16;
#pragma unroll
    for (int h = 0; h < 2; h++) {
        int k0 = kb + h * 8;
        u16x8 o;
#pragma unroll
        for (int i = 0; i < 8; i++) o[i] = f2bf(t[k0 + i][n]);
        *(u16x8*)&Wt[(size_t)(nt + n) * DM + kt + k0] = o;
    }
}

// ---------- gating: scores = x@Wg + bg (fp32 exact), top-2; casts x->bf16; zeroing ----------
__global__ __launch_bounds__(256) void k_gate(const float* __restrict__ x,
                                              const float* __restrict__ Wg,
                                              const float* __restrict__ bg,
                                              ushort* __restrict__ xb,
                                              int* __restrict__ tok_e,
                                              float* __restrict__ tok_w,
                                              int* __restrict__ gcnt,
                                              float* __restrict__ out,
                                              int* __restrict__ slot_token,
                                              int* __restrict__ cursor) {
    __shared__ float wgT[NE][DM];   // 32 KB
    __shared__ int cnt[NE];
    int gb = blockIdx.x, tid = threadIdx.x;
    if (gb == 0 && tid < NE) cursor[tid] = 0;
    if (tid < NE) cnt[tid] = 0;
    {
        float4 z4 = {0.f, 0.f, 0.f, 0.f};
        float4* orow = (float4*)(out + (size_t)gb * 16 * DM);
#pragma unroll
        for (int i = 0; i < 16; i++) orow[i * 256 + tid] = z4;
        int s0 = gb * (PADCAP / NGATE);
        for (int i = tid; i < PADCAP / NGATE; i += 256) slot_token[s0 + i] = -1;
    }
    for (int i = tid; i < DM * NE; i += 256) {
        int d = i >> 3, e = i & 7;
        wgT[e][d] = Wg[i];
    }
    __syncthreads();
    int wave = tid >> 6, lane = tid & 63;
    int n0 = (gb * 4 + wave) * 4;
    const float4* xr[4];
#pragma unroll
    for (int t = 0; t < 4; t++) xr[t] = (const float4*)(x + (size_t)(n0 + t) * DM);

    float acc[4][NE];
#pragma unroll
    for (int t = 0; t < 4; t++)
#pragma unroll
        for (int e = 0; e < NE; e++) acc[t][e] = 0.f;

#pragma unroll
    for (int j = 0; j < 4; j++) {
        float4 xv[4];
#pragma unroll
        for (int t = 0; t < 4; t++) xv[t] = xr[t][j * 64 + lane];
#pragma unroll
        for (int t = 0; t < 4; t++) {
            ushort4 o;
            o.x = f2bf(xv[t].x); o.y = f2bf(xv[t].y);
            o.z = f2bf(xv[t].z); o.w = f2bf(xv[t].w);
            ((ushort4*)xb)[(size_t)(n0 + t) * (DM / 4) + j * 64 + lane] = o;
        }
#pragma unroll
        for (int e = 0; e < NE; e++) {
            float4 wv = ((const float4*)&wgT[e][0])[j * 64 + lane];
#pragma unroll
            for (int t = 0; t < 4; t++) {
                acc[t][e] += xv[t].x * wv.x + xv[t].y * wv.y
                           + xv[t].z * wv.z + xv[t].w * wv.w;
            }
        }
    }
#pragma unroll
    for (int t = 0; t < 4; t++)
#pragma unroll
        for (int e = 0; e < NE; e++) {
#pragma unroll
            for (int off = 32; off >= 1; off >>= 1)
                acc[t][e] += __shfl_xor(acc[t][e], off);
        }
    if (lane < 4) {
        int t = lane, n = n0 + t;
        float sc[NE];
#pragma unroll
        for (int e = 0; e < NE; e++) sc[e] = acc[t][e] + bg[e];
        int e0 = 0; float v0 = sc[0];
#pragma unroll
        for (int e = 1; e < NE; e++) if (sc[e] > v0) { v0 = sc[e]; e0 = e; }
        int e1 = -1; float v1 = -3.0e38f;
#pragma unroll
        for (int e = 0; e < NE; e++) if (e != e0 && sc[e] > v1) { v1 = sc[e]; e1 = e; }
        tok_e[2 * n] = e0;     tok_w[2 * n] = v0;
        tok_e[2 * n + 1] = e1; tok_w[2 * n + 1] = v1;
        atomicAdd(&cnt[e0], 1);
        atomicAdd(&cnt[e1], 1);
    }
    __syncthreads();
    if (tid < NE) gcnt[gb * NE + tid] = cnt[tid];   // plain store, no init needed
}

// ---------- fill + plan: reduce gcnt -> totals, hierarchical cursor, scatter ----------
__global__ __launch_bounds__(256) void k_fillplan(const int* __restrict__ tok_e,
                                                  const float* __restrict__ tok_w,
                                                  const int* __restrict__ gcnt,
                                                  int* __restrict__ cursor,
                                                  int* __restrict__ slot_token,
                                                  float* __restrict__ slot_w,
                                                  int* __restrict__ tile_e,
                                                  int* __restrict__ tile_b,
                                                  int* __restrict__ ntiles) {
    __shared__ int lcnt[NE], lbase[NE], wsum[4][NE];
    int tid = threadIdx.x;
    if (tid < NE) lcnt[tid] = 0;
    int tot[NE];
#pragma unroll
    for (int e = 0; e < NE; e++) tot[e] = 0;
    for (int r = tid; r < NGATE; r += 256)
#pragma unroll
        for (int e = 0; e < NE; e++) tot[e] += gcnt[r * NE + e];
#pragma unroll
    for (int e = 0; e < NE; e++)
#pragma unroll
        for (int off = 32; off >= 1; off >>= 1) tot[e] += __shfl_xor(tot[e], off);
    int wave = tid >> 6, lane = tid & 63;
    if (lane == 0)
#pragma unroll
        for (int e = 0; e < NE; e++) wsum[wave][e] = tot[e];
    __syncthreads();   // publishes wsum + lcnt zero
#pragma unroll
    for (int e = 0; e < NE; e++)
        tot[e] = wsum[0][e] + wsum[1][e] + wsum[2][e] + wsum[3][e];

    int n = blockIdx.x * 256 + tid;
    int e0 = tok_e[2 * n],     e1 = tok_e[2 * n + 1];
    float w0 = tok_w[2 * n],   w1 = tok_w[2 * n + 1];
    int p0 = atomicAdd(&lcnt[e0], 1);
    int p1 = atomicAdd(&lcnt[e1], 1);
    __syncthreads();
    if (tid < NE) lbase[tid] = atomicAdd(&cursor[tid], lcnt[tid]);
    if (blockIdx.x == 0 && tid == 32) {   // different wave than the cursor atomics
        int t = 0, o2 = 0;
        for (int e = 0; e < NE; e++) {
            int nt = (tot[e] + BM - 1) / BM;
            for (int i = 0; i < nt; i++) { tile_e[t] = e; tile_b[t] = o2 + i * BM; t++; }
            o2 += nt * BM;
        }
        *ntiles = t;
    }
    __syncthreads();
    int base[NE]; int off = 0;
#pragma unroll
    for (int e = 0; e < NE; e++) {
        base[e] = off;
        off += ((tot[e] + BM - 1) / BM) * BM;
    }
    int s0 = base[e0] + lbase[e0] + p0;
    slot_token[s0] = n; slot_w[s0] = w0;
    int s1 = base[e1] + lbase[e1] + p1;
    slot_token[s1] = n; slot_w[s1] = w1;
}

// ---------- grouped GEMM (R12 core, persistent 2-tile) + embedded W2 transpose ----------
// blocks [0,1088): gemm, 8 XCD x 136 slots, 2 tiles each; R11/R12 inner loop verbatim.
// blocks [1088,3136) (PHASE-1 grid only): W2 transpose tiles; they dispatch after the
// gemm blocks and backfill CU slots as gemm rounds drain -> W2T off the serial path.
// LDS: 24KB union (gemm As/Bs 24KB | transpose float[64][65] 16.6KB).
template <int PHASE>
__global__ __launch_bounds__(256) void k_gemm(const ushort* __restrict__ A,
                                              const ushort* __restrict__ Wt,
                                              const float* __restrict__ bias,
                                              const int* __restrict__ slot_token,
                                              const float* __restrict__ slot_w,
                                              const int* __restrict__ tile_e,
                                              const int* __restrict__ tile_b,
                                              const int* __restrict__ ntiles,
                                              ushort* __restrict__ Hout,
                                              float* __restrict__ out,
                                              const float* __restrict__ W2src,
                                              ushort* __restrict__ w2t_dst) {
    __shared__ ushort smem_raw[12288];   // 24 KB union
    int tid = threadIdx.x;

    if (PHASE == 1 && blockIdx.x >= 8 * MAXTILES) {
        // ---- embedded W2 transpose: w2t[e][n][k] = W2[e][k][n] ----
        int tb = blockIdx.x - 8 * MAXTILES;       // 0..2047
        int e2 = tb >> 8;
        const float* W = W2src + (size_t)e2 * DM * DM;
        ushort* Wt2 = w2t_dst + (size_t)e2 * DM * DM;
        float (*t)[65] = (float(*)[65])smem_raw;  // 16.6 KB view
        int kt = ((tb >> 4) & 15) * 64, nt = (tb & 15) * 64;
        int r16 = tid >> 4, c4 = (tid & 15) * 4;
#pragma unroll
        for (int p = 0; p < 4; p++) {
            int k = p * 16 + r16;
            float4 v = *(const float4*)&W[(size_t)(kt + k) * DM + nt + c4];
            t[k][c4] = v.x; t[k][c4 + 1] = v.y; t[k][c4 + 2] = v.z; t[k][c4 + 3] = v.w;
        }
        __syncthreads();
        int n = tid >> 2, kb = (tid & 3) * 16;
#pragma unroll
        for (int h = 0; h < 2; h++) {
            int k0 = kb + h * 8;
            u16x8 o;
#pragma unroll
            for (int i = 0; i < 8; i++) o[i] = f2bf(t[k0 + i][n]);
            *(u16x8*)&Wt2[(size_t)(nt + n) * DM + kt + k0] = o;
        }
        return;
    }

    ushort (*As)[4096] = (ushort(*)[4096])smem_raw;            // 2 x 8KB
    ushort (*Bs)[2048] = (ushort(*)[2048])(smem_raw + 8192);   // 2 x 4KB

    int wave = tid >> 6, lane = tid & 63, quad = lane >> 4, lm = lane & 15;
    int wm = wave >> 1, wn = wave & 1;
    int sr = lane >> 2;                            // row-in-chunk 0..15
    int gseg = (lane & 3) ^ ((lane >> 4) & 3);     // global 16B-seg (xor swizzle)
    int asel = ((quad ^ (lm >> 2)) & 3) * 8;
    int abase = (wm * 64 + lm) * 32 + asel;
    int bbase = (wn * 32 + lm) * 32 + asel;

    int xcd = blockIdx.x & 7, slot = blockIdx.x >> 3;   // slot 0..135
    int ntv = *ntiles;

#define ISSUE(buf, koff)                                              \
    do {                                                              \
        load_lds16(aptr[0] + (koff), &As[(buf)][(wave * 2 + 0) * 512]); \
        load_lds16(aptr[1] + (koff), &As[(buf)][(wave * 2 + 1) * 512]); \
        load_lds16(bptr + (koff), &Bs[(buf)][wave * 512]);            \
    } while (0)

#define COMPUTE(buf)                                                          \
    do {                                                                      \
        const ushort* Ab = As[(buf)];                                         \
        const ushort* Bb = Bs[(buf)];                                         \
        bf16x8 av[4], bv[2];                                                  \
        _Pragma("unroll")                                                     \
        for (int f = 0; f < 4; f++) av[f] = *(const bf16x8*)&Ab[abase + f * 512]; \
        _Pragma("unroll")                                                     \
        for (int f = 0; f < 2; f++) bv[f] = *(const bf16x8*)&Bb[bbase + f * 512]; \
        __builtin_amdgcn_s_setprio(1);                                        \
        _Pragma("unroll")                                                     \
        for (int fm = 0; fm < 4; fm++)                                        \
            _Pragma("unroll")                                                 \
            for (int fn = 0; fn < 2; fn++)                                    \
                acc[fm][fn] = __builtin_amdgcn_mfma_f32_16x16x32_bf16(        \
                    av[fm], bv[fn], acc[fm][fn], 0, 0, 0);                    \
        __builtin_amdgcn_s_setprio(0);                                        \
    } while (0)

#pragma unroll 1
    for (int j = 0; j < 2; ++j) {
        int wid = xcd * 272 + slot + 136 * j;
        int t = wid >> 4;
        if (t >= ntv) continue;                  // uniform per block -> barrier-safe
        int ncol0 = (wid & 15) << 6;
        int e = tile_e[t];
        int sbase = tile_b[t];
        const ushort* Wte = Wt + (size_t)e * DM * DM;

        const ushort* aptr[2];
        const ushort* bptr;
#pragma unroll
        for (int ci = 0; ci < 2; ci++) {
            int row = (wave * 2 + ci) * 16 + sr;
            int ar;
            if (PHASE == 1) {
                ar = slot_token[sbase + row];
                if (ar < 0) ar = 0;          // pad rows: load row 0, discard in epilogue
            } else {
                ar = sbase + row;
            }
            aptr[ci] = A + (size_t)ar * DM + gseg * 8;
        }
        {
            int brow = wave * 16 + sr;
            bptr = Wte + (size_t)(ncol0 + brow) * DM + gseg * 8;
        }

        f32x4 acc[4][2];
#pragma unroll
        for (int i = 0; i < 4; i++)
#pragma unroll
            for (int jj = 0; jj < 2; jj++) acc[i][jj] = (f32x4){0.f, 0.f, 0.f, 0.f};

        ISSUE(0, 0);
#pragma unroll 2
        for (int it = 0; it < 32; ++it) {
            if (it < 31) {
                ISSUE((it + 1) & 1, (it + 1) * 32);
                __builtin_amdgcn_s_waitcnt(0x0F73);   // vmcnt(3): current buf's 3 done
            } else {
                __builtin_amdgcn_s_waitcnt(0x0F70);   // vmcnt(0): last buf done
            }
            __builtin_amdgcn_s_barrier();
            __builtin_amdgcn_sched_barrier(0);        // ds_reads may not hoist above
            COMPUTE(it & 1);
            __builtin_amdgcn_sched_barrier(0);        // nothing sinks below
            __builtin_amdgcn_s_waitcnt(0xC07F);       // lgkmcnt(0): ds_reads retired
            __builtin_amdgcn_s_barrier();             // readers done before buf re-staged
        }

        // epilogue — C/D layout: col = lane&15, row = quad*4 + r  [m89-verified]
#pragma unroll
        for (int fm = 0; fm < 4; fm++) {
            int rowg = wm * 64 + fm * 16 + quad * 4;
            if (PHASE == 1) {
#pragma unroll
                for (int fn = 0; fn < 2; fn++) {
                    int col = ncol0 + wn * 32 + fn * 16 + lm;
                    float bv2 = bias[e * DM + col];
#pragma unroll
                    for (int r = 0; r < 4; r++) {
                        float v = acc[fm][fn][r] + bv2;
                        v = fmaxf(v, 0.f);
                        Hout[(size_t)(sbase + rowg + r) * DM + col] = f2bf(v);
                    }
                }
            } else {
                int tk[4]; float wv[4];
#pragma unroll
                for (int r = 0; r < 4; r++) {
                    tk[r] = slot_token[sbase + rowg + r];
                    wv[r] = slot_w[sbase + rowg + r];
                }
#pragma unroll
                for (int fn = 0; fn < 2; fn++) {
                    int col = ncol0 + wn * 32 + fn * 16 + lm;
                    float bv2 = bias[e * DM + col];
#pragma unroll
                    for (int r = 0; r < 4; r++) {
                        if (tk[r] >= 0) {
                            float v = wv[r] * (acc[fm][fn][r] + bv2);
                            atomicAdd(&out[(size_t)tk[r] * DM + col], v);
                        }
                    }
                }
            }
        }
    }
#undef ISSUE
#undef COMPUTE
}

extern "C" void kernel_launch(void* const* d_in, const int* in_sizes, int n_in,
                              void* d_out, int out_size, void* d_ws, size_t ws_size,
                              hipStream_t stream) {
    const float* x  = (const float*)d_in[0];
    const float* Wg = (const float*)d_in[1];
    const float* bg = (const float*)d_in[2];
    const float* W1 = (const float*)d_in[3];
    const float* b1 = (const float*)d_in[4];
    const float* W2 = (const float*)d_in[5];
    const float* b2 = (const float*)d_in[6];
    float* out = (float*)d_out;

    char* ws = (char*)d_ws;
    // workspace layout (bytes) — total ~86.3 MB
    ushort* xb         = (ushort*)(ws + 0);            // 16 MB
    ushort* w1t        = (ushort*)(ws + 16777216);     // 16 MB
    ushort* w2t        = (ushort*)(ws + 33554432);     // 16 MB
    ushort* H          = (ushort*)(ws + 50331648);     // 34 MB (PADCAP*DM*2)
    int*    tok_e      = (int*)  (ws + 85983232);
    float*  tok_w      = (float*)(ws + 86048768);
    int*    slot_token = (int*)  (ws + 86114304);
    float*  slot_w     = (float*)(ws + 86183936);
    int*    cursor     = (int*)  (ws + 86253568);
    int*    tile_e     = cursor + 16;
    int*    tile_b     = tile_e + MAXTILES;
    int*    ntiles     = tile_b + MAXTILES;
    int*    gcnt       = (int*)  (ws + 86257664);      // 512*8 ints = 16 KB

    k_gate<<<NGATE, 256, 0, stream>>>(x, Wg, bg, xb, tok_e, tok_w,
                                      gcnt, out, slot_token, cursor);
    dim3 t1(16, 16, 8);
    k_transpose1<<<t1, 256, 0, stream>>>(W1, w1t);
    k_fillplan<<<NTOK / 256, 256, 0, stream>>>(tok_e, tok_w, gcnt, cursor,
                                               slot_token, slot_w,
                                               tile_e, tile_b, ntiles);

    // GEMM1 (1088 persistent gemm blocks) + 2048 embedded W2-transpose blocks
    k_gemm<1><<<8 * MAXTILES + 2048, 256, 0, stream>>>(
        xb, w1t, b1, slot_token, slot_w, tile_e, tile_b, ntiles,
        H, nullptr, W2, w2t);
    k_gemm<2><<<8 * MAXTILES, 256, 0, stream>>>(
        H, w2t, b2, slot_token, slot_w, tile_e, tile_b, ntiles,
        nullptr, out, nullptr, nullptr);
}